// Round 5
// baseline (10903.241 us; speedup 1.0000x reference)
//
#include <hip/hip_runtime.h>
#include <hip/hip_bf16.h>

// NeuralODE Bosh3 fixed-step integrator, persistent-block formulation.
// Round 5: 128 blocks x 512 thr (8 waves, Btile=16), launch_bounds(512,2)
// (256-VGPR cap), static deep register prefetch of weight fragments
// (8 loads in flight/wave), A-fragments loaded once per eval, cooperative
// full-line nt output stores staged through LDS (kills RMW write-amp).

#define B_ 2048
#define L_ 128
#define P_ 8
#define W_ 512
#define T_ 128
#define BT_ 16
#define NBLK (B_/BT_)          // 128 blocks

typedef __attribute__((ext_vector_type(8))) short short8;
typedef __attribute__((ext_vector_type(4))) float f32x4;

// packed weight sizes (ushort elements)
#define W0P_ELEMS (32*5*64*8)    // N=512 (32 nt), Kpad=160 (5 kt)
#define W1P_ELEMS (32*16*64*8)   // N=512, K=512 (16 kt)
#define W2P_ELEMS (8*16*64*8)    // N=128 (8 nt), K=512
#define W1P_OFF (W0P_ELEMS)
#define W2P_OFF (W0P_ELEMS + W1P_ELEMS)
#define WTOT (W0P_ELEMS + W1P_ELEMS + W2P_ELEMS)   // 409600 ushorts = 819200 B

__device__ __forceinline__ unsigned short f2bf(float f){
  unsigned u = __builtin_bit_cast(unsigned, f);
  u += 0x7fffu + ((u >> 16) & 1u);          // round-to-nearest-even
  return (unsigned short)(u >> 16);
}

__device__ __forceinline__ float tanh_fast(float x){
  float e = __expf(2.0f * x);
  return 1.0f - __fdividef(2.0f, e + 1.0f); // exact at saturation (+-1)
}

// Pack W[n][k] (row-major fp32) into MFMA B-fragments:
// dst[((nt*KT + kt)*64 + lane)*8 + j] = bf16(W[nt*16+(lane&15)][kt*32+(lane>>4)*8+j])
// idx in [WTOT, WTOT+T_-1): dts[idx-WTOT] = ts[i+1]-ts[i] (fp32) at wp+WTOT.
__global__ void prep_weights(const float* __restrict__ W0,
                             const float* __restrict__ W1,
                             const float* __restrict__ W2,
                             const float* __restrict__ ts,
                             unsigned short* __restrict__ wp){
  int idx = blockIdx.x * blockDim.x + threadIdx.x;
  if (idx >= WTOT){
    int t = idx - WTOT;
    if (t < T_ - 1){
      float* dts = (float*)(wp + WTOT);
      dts[t] = ts[t+1] - ts[t];
    }
    return;
  }
  const float* src; int base, KT, Korig;
  if (idx < W1P_OFF)      { src = W0; base = 0;       KT = 5;  Korig = 136; }
  else if (idx < W2P_OFF) { src = W1; base = W1P_OFF; KT = 16; Korig = 512; }
  else                    { src = W2; base = W2P_OFF; KT = 16; Korig = 512; }
  int e    = idx - base;
  int j    = e & 7;
  int frag = e >> 3;
  int lane = frag & 63;
  int tile = frag >> 6;
  int kt   = tile % KT;
  int nt   = tile / KT;
  int row  = nt*16 + (lane & 15);
  int k    = kt*32 + ((lane >> 4) << 3) + j;
  float v  = (k < Korig) ? src[row*Korig + k] : 0.0f;
  wp[idx] = f2bf(v);
}

// LDS layouts (bf16, XOR-swizzled: byte ^= (row&7)<<4 within the row).
#define XROWB 384    // x: 192 ushorts/row (0..127 y, 128..135 args, rest 0)
#define HROWB 1024   // h: 512 ushorts/row

__global__ __launch_bounds__(512, 2)
void ode_main(const float* __restrict__ x0,
              const float* __restrict__ args,
              const float* __restrict__ b0, const float* __restrict__ b1,
              const float* __restrict__ b2,
              const unsigned short* __restrict__ wp,
              float* __restrict__ out){
  __shared__ __align__(16) unsigned short xb[BT_*(XROWB/2)];   // 6 KiB
  __shared__ __align__(16) unsigned short h1[BT_*(HROWB/2)];   // 16 KiB
  __shared__ __align__(16) unsigned short h2[BT_*(HROWB/2)];   // 16 KiB
  __shared__ __align__(16) float ybuf[BT_][L_];                // 8 KiB fp32 state

  const int tid  = threadIdx.x;
  const int lane = tid & 63;
  const int wv   = tid >> 6;     // wave 0..7
  const int lo   = lane & 15;
  const int hi   = lane >> 4;    // 0..3
  const int r0   = blockIdx.x * BT_;

  const unsigned short* w0p = wp;
  const unsigned short* w1p = wp + W1P_OFF;
  const unsigned short* w2p = wp + W2P_OFF;
  const float* dts = (const float*)(wp + WTOT);

  // zero x buffer (zeroes are swizzle-invariant)
  for (int i = tid; i < BT_*(XROWB/2); i += 512) xb[i] = 0;
  __syncthreads();

  // args -> x cols 128..135 (constant across all steps)
  if (tid < BT_*P_){
    int r = tid >> 3, pp = tid & 7;
    unsigned short v = f2bf(args[(r0 + r)*P_ + pp]);
    *(unsigned short*)((char*)xb + r*XROWB + (((128 + pp)*2) ^ ((r & 7) << 4))) = v;
  }

  // per-wave A-read bases (row = lo), swizzle keyed by lo
  const char* xa  = (const char*)xb + lo*XROWB;
  const char* h1a = (const char*)h1 + lo*HROWB;
  const char* h2a = (const char*)h2 + lo*HROWB;
  const int aswz  = (lo & 7) << 4;

  // per-thread write bases (rows 4*hi+j)
  char* h1w[4]; char* h2w[4]; char* xbw[4]; int wswz[4];
  #pragma unroll
  for (int j = 0; j < 4; ++j){
    int rj = 4*hi + j;
    h1w[j] = (char*)h1 + rj*HROWB;
    h2w[j] = (char*)h2 + rj*HROWB;
    xbw[j] = (char*)xb + rj*XROWB;
    wswz[j] = (rj & 7) << 4;
  }

  // biases for this wave's N-tiles (nt = wv+8i in layers 1/2)
  float b0v[4], b1v[4];
  #pragma unroll
  for (int i = 0; i < 4; ++i){
    b0v[i] = b0[(wv + 8*i)*16 + lo];
    b1v[i] = b1[(wv + 8*i)*16 + lo];
  }

  // ODE state: every wave owns layer-3 tile nt=wv; rows 4hi+j, col c3
  const int c3 = wv*16 + lo;
  float yr[4], yn[4];
  float b2v = b2[c3];
  #pragma unroll
  for (int j = 0; j < 4; ++j){
    int row = 4*hi + j;
    float v = x0[(r0 + row)*L_ + c3];
    yr[j] = v;
    ybuf[row][c3] = v;
    *(unsigned short*)(xbw[j] + ((c3*2) ^ wswz[j])) = f2bf(v);
  }

  // One vector-field eval: x(LDS) -> h1 -> h2 -> d (layer-3 accum, no bias).
  // Weight B-fragments stream through static double-buffered register
  // pipelines (8 x 16B loads in flight per wave).
  auto evalf = [&](f32x4& dout){
    // ---- layer 1: K=160 (5 kt), N=512; nt = wv+8i
    {
      short8 a1[5];
      #pragma unroll
      for (int q = 0; q < 5; ++q)
        a1[q] = *(const short8*)(xa + ((q*64 + hi*16) ^ aswz));
      short8 bA[5], bB[5];
      {
        const unsigned short* wb = w0p + (wv*5*64 + lane)*8;
        #pragma unroll
        for (int q = 0; q < 5; ++q) bA[q] = *(const short8*)(wb + q*512);
      }
      #pragma unroll
      for (int i = 0; i < 4; ++i){
        if (i < 3){
          const unsigned short* wb = w0p + ((wv + 8*(i+1))*5*64 + lane)*8;
          #pragma unroll
          for (int q = 0; q < 5; ++q)
            (i & 1 ? bA : bB)[q] = *(const short8*)(wb + q*512);
        }
        f32x4 acc = {0.f,0.f,0.f,0.f};
        #pragma unroll
        for (int q = 0; q < 5; ++q)
          acc = __builtin_amdgcn_mfma_f32_16x16x32_bf16(a1[q], (i & 1 ? bB : bA)[q], acc, 0, 0, 0);
        #pragma unroll
        for (int j = 0; j < 4; ++j){
          float v = tanh_fast(acc[j] + b0v[i]);
          int col = (wv + 8*i)*16 + lo;
          *(unsigned short*)(h1w[j] + ((col*2) ^ wswz[j])) = f2bf(v);
        }
      }
    }
    __syncthreads();
    // ---- layer 2: K=512 (16 kt), N=512; nt = wv+8i, half-nt pipeline
    {
      short8 a2[16];
      #pragma unroll
      for (int q = 0; q < 16; ++q)
        a2[q] = *(const short8*)(h1a + ((q*64 + hi*16) ^ aswz));
      short8 cA[8], cB[8];
      {
        const unsigned short* wb = w1p + (wv*16*64 + lane)*8;   // (nt0, half0)
        #pragma unroll
        for (int q = 0; q < 8; ++q) cA[q] = *(const short8*)(wb + q*512);
      }
      f32x4 acc = {0.f,0.f,0.f,0.f};
      #pragma unroll
      for (int s = 0; s < 8; ++s){
        const int i = s >> 1, h = s & 1;
        if (s < 7){
          const int ni = (s+1) >> 1, nh = (s+1) & 1;
          const unsigned short* wb = w1p + (((wv + 8*ni)*16 + nh*8)*64 + lane)*8;
          #pragma unroll
          for (int q = 0; q < 8; ++q)
            (s & 1 ? cA : cB)[q] = *(const short8*)(wb + q*512);
        }
        if (h == 0) acc = f32x4{0.f,0.f,0.f,0.f};
        #pragma unroll
        for (int q = 0; q < 8; ++q)
          acc = __builtin_amdgcn_mfma_f32_16x16x32_bf16(a2[h*8+q], (s & 1 ? cB : cA)[q], acc, 0, 0, 0);
        if (h == 1){
          #pragma unroll
          for (int j = 0; j < 4; ++j){
            float v = tanh_fast(acc[j] + b1v[i]);
            int col = (wv + 8*i)*16 + lo;
            *(unsigned short*)(h2w[j] + ((col*2) ^ wswz[j])) = f2bf(v);
          }
        }
      }
    }
    __syncthreads();
    // ---- layer 3: K=512 (16 kt), N=128; wave wv owns nt = wv
    {
      short8 dA[8], dB[8];
      {
        const unsigned short* wb = w2p + (wv*16*64 + lane)*8;
        #pragma unroll
        for (int q = 0; q < 8; ++q) dA[q] = *(const short8*)(wb + q*512);
        #pragma unroll
        for (int q = 0; q < 8; ++q) dB[q] = *(const short8*)(wb + 4096 + q*512);
      }
      short8 a3[16];
      #pragma unroll
      for (int q = 0; q < 16; ++q)
        a3[q] = *(const short8*)(h2a + ((q*64 + hi*16) ^ aswz));
      f32x4 acc = {0.f,0.f,0.f,0.f};
      #pragma unroll
      for (int q = 0; q < 8; ++q)
        acc = __builtin_amdgcn_mfma_f32_16x16x32_bf16(a3[q], dA[q], acc, 0, 0, 0);
      #pragma unroll
      for (int q = 0; q < 8; ++q)
        acc = __builtin_amdgcn_mfma_f32_16x16x32_bf16(a3[8+q], dB[q], acc, 0, 0, 0);
      dout = acc;
    }
  };

  // Bosh3 loop. ybuf holds y_{t-1}; cooperative full-line nt store at loop top.
  for (int t = 1; t < T_; ++t){
    float dt = dts[t-1];
    f32x4 d;

    __syncthreads();                       // xb + ybuf ready
    {                                      // store y_{t-1}: 16 rows x 512 B
      int row = tid >> 5, c4 = (tid & 31) << 2;
      f32x4 v = *(const f32x4*)&ybuf[row][c4];
      __builtin_nontemporal_store(v, (f32x4*)&out[((r0 + row)*T_ + (t-1))*L_ + c4]);
    }

    evalf(d);                              // k1
    #pragma unroll
    for (int j = 0; j < 4; ++j){
      float k = d[j] + b2v;
      yn[j] = yr[j] + dt*(2.0f/9.0f)*k;
      float xs = yr[j] + 0.5f*dt*k;
      *(unsigned short*)(xbw[j] + ((c3*2) ^ wswz[j])) = f2bf(xs);
    }

    __syncthreads();
    evalf(d);                              // k2
    #pragma unroll
    for (int j = 0; j < 4; ++j){
      float k = d[j] + b2v;
      yn[j] += dt*(1.0f/3.0f)*k;
      float xs = yr[j] + 0.75f*dt*k;
      *(unsigned short*)(xbw[j] + ((c3*2) ^ wswz[j])) = f2bf(xs);
    }

    __syncthreads();
    evalf(d);                              // k3
    #pragma unroll
    for (int j = 0; j < 4; ++j){
      float k = d[j] + b2v;
      yn[j] += dt*(4.0f/9.0f)*k;
      yr[j] = yn[j];
      int row = 4*hi + j;
      ybuf[row][c3] = yr[j];
      *(unsigned short*)(xbw[j] + ((c3*2) ^ wswz[j])) = f2bf(yr[j]);
    }
  }

  // final slice t = T_-1
  __syncthreads();
  {
    int row = tid >> 5, c4 = (tid & 31) << 2;
    f32x4 v = *(const f32x4*)&ybuf[row][c4];
    __builtin_nontemporal_store(v, (f32x4*)&out[((r0 + row)*T_ + (T_-1))*L_ + c4]);
  }
}

extern "C" void kernel_launch(void* const* d_in, const int* in_sizes, int n_in,
                              void* d_out, int out_size, void* d_ws, size_t ws_size,
                              hipStream_t stream) {
  const float* x0   = (const float*)d_in[0];
  const float* ts   = (const float*)d_in[1];
  const float* args = (const float*)d_in[2];
  const float* W0   = (const float*)d_in[3];
  const float* b0   = (const float*)d_in[4];
  const float* W1   = (const float*)d_in[5];
  const float* b1   = (const float*)d_in[6];
  const float* W2   = (const float*)d_in[7];
  const float* b2   = (const float*)d_in[8];
  unsigned short* wp = (unsigned short*)d_ws;   // 819,200 B weights + 512 B dts
  float* out = (float*)d_out;

  prep_weights<<<(WTOT + T_ + 255)/256, 256, 0, stream>>>(W0, W1, W2, ts, wp);
  ode_main<<<NBLK, 512, 0, stream>>>(x0, args, b0, b1, b2, wp, out);
}